// Round 6
// baseline (556.285 us; speedup 1.0000x reference)
//
#include <hip/hip_runtime.h>
#include <cstdint>
#include <cstddef>

// ---------------------------------------------------------------------------
// GenEdge R6:
//   cvt    : f32 -> unit-norm f16 tiled layout (write-coalesced) + gmax=0.
//   edge   : 4-wave workgroups (no barriers; waves independent) to beat the
//            per-CU workgroup-slot occupancy cap seen with 1-wave blocks.
//            Each wave: 32 output cols x 13-or-12 di. Weight algebra hoisted
//            (di-invariant parts precomputed; per-di kx/ky = 3 VALU/slot-12).
//            A in regs, B streamed per-ks (4 frags live), acc in AGPR.
//   combine: sum halves, e=|gx|+|gy| (border zeroed), block-max -> atomicMax.
//   norm   : divide by global max.
// ---------------------------------------------------------------------------

typedef _Float16 half8 __attribute__((ext_vector_type(8)));
typedef float    f32x4 __attribute__((ext_vector_type(4)));

#define HW   400
#define NP   (HW*HW)
#define CCH  128
#define W16  416                 // padded width (26 groups of 16)
#define ROWE (W16*CCH)           // 53248 f16 elements per padded row
#define PAD  12
#define IEND 388                 // interior: [12, 388)

// f16 cube layout per row: [pg(26)][ks(4)][q(4)][i(16)][j(8)] elements
// offset = pg*2048 + ks*512 + q*128 + i*8 + j
// => a wave's B-frag load for (group, ks) is base + lane*16 B: one coalesced
//    global_load_dwordx4 per (sg, ks).

// acos with the reference's +/-0.999999 clip folded in: |err| <= 6.7e-5 rad.
__device__ __forceinline__ float acos_clip(float x) {
  float ax = fminf(fabsf(x), 0.999999f);     // one inst (abs modifier free)
  float s  = __builtin_amdgcn_sqrtf(1.0f - ax);
  float p  = fmaf(ax, -0.0187292994f, 0.0742610134f);
  p = fmaf(p, ax, -0.2121143967f);
  p = fmaf(p, ax,  1.5707287572f);
  float r = s * p;
  return (x >= 0.0f) ? r : (3.14159265359f - r);
}

// ---------------- Phase 1: convert + normalize (write-coalesced) -----------
__global__ void cvt_kernel(const float* __restrict__ cube,
                           _Float16* __restrict__ c16,
                           unsigned* __restrict__ gmax) {
  __shared__ float part[64];    // [i*4 + ks]
  int pg = blockIdx.x;          // 0..25 (pg 25 is all-pad)
  int r  = blockIdx.y;          // 0..399
  int t  = threadIdx.x;         // 0..255: t = ks*64 + q*16 + i
  if (pg == 0 && r == 0 && t == 0) *gmax = 0u;   // every call (re-poisoned ws)
  int i  = t & 15;
  int q  = (t >> 4) & 3;
  int ks = t >> 6;
  int px = pg*16 + i;
  float v[8];
  if (px < HW) {
    const float* src = cube + ((size_t)(r*HW + px))*CCH + ks*32 + q*8;
    #pragma unroll
    for (int j = 0; j < 8; ++j) v[j] = src[j];
  } else {
    #pragma unroll
    for (int j = 0; j < 8; ++j) v[j] = 0.f;
  }
  float ss = 0.f;
  #pragma unroll
  for (int j = 0; j < 8; ++j) ss += v[j]*v[j];
  ss += __shfl_xor(ss, 16);
  ss += __shfl_xor(ss, 32);
  if (q == 0) part[i*4 + ks] = ss;
  __syncthreads();
  f32x4 pp = *(const f32x4*)&part[i*4];
  float tot = pp.x + pp.y + pp.z + pp.w;
  float sc = (tot > 0.f) ? rsqrtf(tot) : 0.f;
  half8 hv;
  #pragma unroll
  for (int j = 0; j < 8; ++j) hv[j] = (_Float16)(v[j]*sc);
  *(half8*)(c16 + (size_t)r*ROWE + pg*2048 + t*8) = hv;
}

// ---------------- Phase 2: banded MFMA + SAD partials ----------------
__global__ __launch_bounds__(256, 6) void edge_kernel(
    const _Float16* __restrict__ c16,
    float* __restrict__ gxp, float* __restrict__ gyp) {
  // 2256 blocks = 8 XCDs x 282; each XCD gets a contiguous ~47-row band.
  // Block -> (h, sub); 4 waves take (wb = sub*2 + wv/2, half = wv&1).
  const int id  = blockIdx.x;
  const int g   = (id & 7)*282 + (id >> 3);
  const int gh  = g / 6;
  const int sub = g - gh*6;
  const int h   = gh + PAD;              // 12..387
  const int wv  = threadIdx.x >> 6;
  const int l   = threadIdx.x & 63;
  const int wb   = sub*2 + (wv >> 1);    // 0..11
  const int half = wv & 1;               // di range half
  const int c  = l & 15, q = l >> 4;
  const int w0 = PAD + 32*wb;
  const int g0 = 2*wb;                   // first B pixel-group (s0 = 32*wb)

  // A-frags: center pixels of row h.  A[m=lane&15][k=q*8+j]
  half8 A[2][4];
  #pragma unroll
  for (int t = 0; t < 2; ++t) {
    int px = w0 + 16*t + c;              // <= 395 < 400
    const _Float16* p = c16 + (size_t)h*ROWE + (px >> 4)*2048 + q*128 + (px & 15)*8;
    #pragma unroll
    for (int ks = 0; ks < 4; ++ks)
      A[t][ks] = *(const half8*)(p + ks*512);
  }

  // di-invariant weight pieces for the 12 (d,rr) slots (t-invariant):
  // dj-12 = 16d - 12 - rr + (c-4q)
  const float cq = (float)(c - 4*q);
  float p_m[12], sg_m[12], mn_m[12], one_m[12];
  #pragma unroll
  for (int d = 0; d < 3; ++d)
    #pragma unroll
    for (int rr = 0; rr < 4; ++rr) {
      int j = d*4 + rr;
      float p  = cq + (float)(16*d - 12 - rr);
      float ap = fabsf(p);
      bool  ok = ap <= 12.f;
      p_m[j]  = ok ? p : 0.f;
      sg_m[j] = ok ? fminf(fmaxf(p, -1.f), 1.f) : 0.f;
      mn_m[j] = ok ? (12.f - ap) : 0.f;    // mnj = 12-|dj-12|
      one_m[j]= ok ? 1.f : 0.f;
    }

  float gx[2][4], gy[2][4];
  #pragma unroll
  for (int t = 0; t < 2; ++t)
    #pragma unroll
    for (int rr = 0; rr < 4; ++rr) { gx[t][rr] = 0.f; gy[t][rr] = 0.f; }

  const _Float16* bBase = c16 + g0*2048 + (size_t)l*8;
  const int diLo = half ? 13 : 0;
  const int diHi = half ? 25 : 13;

  #pragma unroll 1
  for (int di = diLo; di < diHi; ++di) {
    const int r = h + di - PAD;          // 0..399
    const _Float16* rowB = bBase + (size_t)r*ROWE;

    f32x4 acc[2][3];
    #pragma unroll
    for (int t = 0; t < 2; ++t)
      #pragma unroll
      for (int d = 0; d < 3; ++d) acc[t][d] = (f32x4){0.f,0.f,0.f,0.f};

    #pragma unroll
    for (int ks = 0; ks < 4; ++ks) {
      half8 B0 = *(const half8*)(rowB + 0*2048 + ks*512);
      half8 B1 = *(const half8*)(rowB + 1*2048 + ks*512);
      half8 B2 = *(const half8*)(rowB + 2*2048 + ks*512);
      half8 B3 = *(const half8*)(rowB + 3*2048 + ks*512);
      acc[0][0] = __builtin_amdgcn_mfma_f32_16x16x32_f16(A[0][ks], B0, acc[0][0], 0,0,0);
      acc[0][1] = __builtin_amdgcn_mfma_f32_16x16x32_f16(A[0][ks], B1, acc[0][1], 0,0,0);
      acc[0][2] = __builtin_amdgcn_mfma_f32_16x16x32_f16(A[0][ks], B2, acc[0][2], 0,0,0);
      acc[1][0] = __builtin_amdgcn_mfma_f32_16x16x32_f16(A[1][ks], B1, acc[1][0], 0,0,0);
      acc[1][1] = __builtin_amdgcn_mfma_f32_16x16x32_f16(A[1][ks], B2, acc[1][1], 0,0,0);
      acc[1][2] = __builtin_amdgcn_mfma_f32_16x16x32_f16(A[1][ks], B3, acc[1][2], 0,0,0);
    }

    // per-di weights (ii/sdi/dif wave-uniform -> SALU): 3 VALU per slot-12
    const float ii  = (float)((di <= 12) ? di : 24 - di);
    const float sdi = (float)((di > 12) - (di < 12));
    const float dif = (float)(di - 12);
    float kx[12], ky[12];
    #pragma unroll
    for (int j = 0; j < 12; ++j) {
      kx[j] = fmaf(sg_m[j], ii, p_m[j]);
      ky[j] = fmaf(sdi, mn_m[j], dif*one_m[j]);
    }

    #pragma unroll
    for (int t = 0; t < 2; ++t)
      #pragma unroll
      for (int d = 0; d < 3; ++d)
        #pragma unroll
        for (int rr = 0; rr < 4; ++rr) {
          int   j   = d*4 + rr;
          float sad = acos_clip(acc[t][d][rr]);   // cos from unit vectors
          gx[t][rr] = fmaf(sad, kx[j], gx[t][rr]);
          gy[t][rr] = fmaf(sad, ky[j], gy[t][rr]);
        }
  }

  // reduce over c (lane bits 0..3); writer lanes c == rr store partials
  const int hoff = half*NP + h*HW;
  #pragma unroll
  for (int t = 0; t < 2; ++t)
    #pragma unroll
    for (int rr = 0; rr < 4; ++rr) {
      float sgx = gx[t][rr], sgy = gy[t][rr];
      #pragma unroll
      for (int m = 1; m < 16; m <<= 1) {
        sgx += __shfl_xor(sgx, m);
        sgy += __shfl_xor(sgy, m);
      }
      if (c == rr) {
        int w = w0 + 16*t + 4*q + rr;    // <= 395
        gxp[hoff + w] = sgx;
        gyp[hoff + w] = sgy;
      }
    }
}

// ---------------- Phase 3a: combine halves + global max ----------------
__global__ void combine_kernel(float* __restrict__ gxp,
                               const float* __restrict__ gyp,
                               unsigned* __restrict__ gmax) {
  __shared__ float wm[4];
  int idx = blockIdx.x*256 + threadIdx.x;      // 625*256 = NP exactly
  int hh = idx / HW;
  int ww = idx - hh*HW;
  float e = 0.f;
  if (hh >= PAD && hh < IEND && ww >= PAD && ww < IEND)
    e = fabsf(gxp[idx] + gxp[NP + idx]) + fabsf(gyp[idx] + gyp[NP + idx]);
  gxp[idx] = e;                                // edge buffer aliases gxp[0]
  float m = e;
  #pragma unroll
  for (int off = 1; off < 64; off <<= 1) m = fmaxf(m, __shfl_xor(m, off));
  if ((threadIdx.x & 63) == 0) wm[threadIdx.x >> 6] = m;
  __syncthreads();
  if (threadIdx.x == 0) {
    float mm = fmaxf(fmaxf(wm[0], wm[1]), fmaxf(wm[2], wm[3]));
    atomicMax(gmax, __float_as_uint(mm));      // e >= 0: uint order ok
  }
}

// ---------------- Phase 3b: normalize ----------------
__global__ void norm_kernel(const float* __restrict__ edge,
                            const unsigned* __restrict__ gmax,
                            float* __restrict__ out) {
  int idx = blockIdx.x*256 + threadIdx.x;
  float mv = __uint_as_float(*gmax);
  out[idx] = edge[idx] / mv;                   // border already 0
}

// ---------------- launch ----------------
extern "C" void kernel_launch(void* const* d_in, const int* in_sizes, int n_in,
                              void* d_out, int out_size, void* d_ws, size_t ws_size,
                              hipStream_t stream) {
  const float* cube = (const float*)d_in[0];   // (1,400,400,128) f32
  char* ws = (char*)d_ws;
  _Float16* c16  = (_Float16*)(ws);                     // 42,598,400 B
  float*    gxp  = (float*)(ws + 42598400);             // 2*NP floats
  float*    gyp  = (float*)(ws + 42598400 + 8*NP);      // 2*NP floats
  unsigned* gmax = (unsigned*)(ws + 42598400 + 16*NP);  // 4 B  (~45.2 MB total)

  cvt_kernel<<<dim3(26, 400), 256, 0, stream>>>(cube, c16, gmax);
  edge_kernel<<<2256, 256, 0, stream>>>(c16, gxp, gyp);
  combine_kernel<<<NP/256, 256, 0, stream>>>(gxp, gyp, gmax);
  norm_kernel<<<NP/256, 256, 0, stream>>>(gxp, gmax, (float*)d_out);
}

// Round 7
// 296.120 us; speedup vs baseline: 1.8786x; 1.8786x over previous
//
#include <hip/hip_runtime.h>
#include <cstdint>
#include <cstddef>

// ---------------------------------------------------------------------------
// GenEdge R7:
//   cvt    : f32 -> unit-norm f16 tiled layout (write-coalesced) + gmax=0.
//   edge   : 4-wave workgroups (no barriers; waves independent) to beat the
//            per-CU workgroup-slot occupancy cap (R6 proved: 35->55% occ).
//            __launch_bounds__(256, 4): 128-VGPR budget -- the kernel needs
//            ~64; R6's (256,6)=85-cap made the allocator pick 40 and SPILL
//            (FETCH 1.3GB). Never push this kernel below ~64 VGPRs.
//   combine: sum halves, e=|gx|+|gy| (border zeroed), block-max -> atomicMax.
//   norm   : divide by global max.
// ---------------------------------------------------------------------------

typedef _Float16 half8 __attribute__((ext_vector_type(8)));
typedef float    f32x4 __attribute__((ext_vector_type(4)));

#define HW   400
#define NP   (HW*HW)
#define CCH  128
#define W16  416                 // padded width (26 groups of 16)
#define ROWE (W16*CCH)           // 53248 f16 elements per padded row
#define PAD  12
#define IEND 388                 // interior: [12, 388)

// f16 cube layout per row: [pg(26)][ks(4)][q(4)][i(16)][j(8)] elements
// offset = pg*2048 + ks*512 + q*128 + i*8 + j
// => a wave's B-frag load for (group, ks) is base + lane*16 B: one coalesced
//    global_load_dwordx4 per (sg, ks).

// acos with the reference's +/-0.999999 clip folded in: |err| <= 6.7e-5 rad.
__device__ __forceinline__ float acos_clip(float x) {
  float ax = fminf(fabsf(x), 0.999999f);     // one inst (abs modifier free)
  float s  = __builtin_amdgcn_sqrtf(1.0f - ax);
  float p  = fmaf(ax, -0.0187292994f, 0.0742610134f);
  p = fmaf(p, ax, -0.2121143967f);
  p = fmaf(p, ax,  1.5707287572f);
  float r = s * p;
  return (x >= 0.0f) ? r : (3.14159265359f - r);
}

// ---------------- Phase 1: convert + normalize (write-coalesced) -----------
__global__ void cvt_kernel(const float* __restrict__ cube,
                           _Float16* __restrict__ c16,
                           unsigned* __restrict__ gmax) {
  __shared__ float part[64];    // [i*4 + ks]
  int pg = blockIdx.x;          // 0..25 (pg 25 is all-pad)
  int r  = blockIdx.y;          // 0..399
  int t  = threadIdx.x;         // 0..255: t = ks*64 + q*16 + i
  if (pg == 0 && r == 0 && t == 0) *gmax = 0u;   // every call (re-poisoned ws)
  int i  = t & 15;
  int q  = (t >> 4) & 3;
  int ks = t >> 6;
  int px = pg*16 + i;
  float v[8];
  if (px < HW) {
    const float* src = cube + ((size_t)(r*HW + px))*CCH + ks*32 + q*8;
    #pragma unroll
    for (int j = 0; j < 8; ++j) v[j] = src[j];
  } else {
    #pragma unroll
    for (int j = 0; j < 8; ++j) v[j] = 0.f;
  }
  float ss = 0.f;
  #pragma unroll
  for (int j = 0; j < 8; ++j) ss += v[j]*v[j];
  ss += __shfl_xor(ss, 16);
  ss += __shfl_xor(ss, 32);
  if (q == 0) part[i*4 + ks] = ss;
  __syncthreads();
  f32x4 pp = *(const f32x4*)&part[i*4];
  float tot = pp.x + pp.y + pp.z + pp.w;
  float sc = (tot > 0.f) ? rsqrtf(tot) : 0.f;
  half8 hv;
  #pragma unroll
  for (int j = 0; j < 8; ++j) hv[j] = (_Float16)(v[j]*sc);
  *(half8*)(c16 + (size_t)r*ROWE + pg*2048 + t*8) = hv;
}

// ---------------- Phase 2: banded MFMA + SAD partials ----------------
__global__ __launch_bounds__(256, 4) void edge_kernel(
    const _Float16* __restrict__ c16,
    float* __restrict__ gxp, float* __restrict__ gyp) {
  // 2256 blocks = 8 XCDs x 282; each XCD gets a contiguous ~47-row band.
  // Block -> (h, sub); 4 waves take (wb = sub*2 + wv/2, half = wv&1).
  const int id  = blockIdx.x;
  const int g   = (id & 7)*282 + (id >> 3);
  const int gh  = g / 6;
  const int sub = g - gh*6;
  const int h   = gh + PAD;              // 12..387
  const int wv  = threadIdx.x >> 6;
  const int l   = threadIdx.x & 63;
  const int wb   = sub*2 + (wv >> 1);    // 0..11
  const int half = wv & 1;               // di range half
  const int c  = l & 15, q = l >> 4;
  const int w0 = PAD + 32*wb;
  const int g0 = 2*wb;                   // first B pixel-group (s0 = 32*wb)

  // A-frags: center pixels of row h.  A[m=lane&15][k=q*8+j]
  half8 A[2][4];
  #pragma unroll
  for (int t = 0; t < 2; ++t) {
    int px = w0 + 16*t + c;              // <= 395 < 400
    const _Float16* p = c16 + (size_t)h*ROWE + (px >> 4)*2048 + q*128 + (px & 15)*8;
    #pragma unroll
    for (int ks = 0; ks < 4; ++ks)
      A[t][ks] = *(const half8*)(p + ks*512);
  }

  // di-invariant weight pieces for the 12 (d,rr) slots (t-invariant):
  // dj-12 = 16d - 12 - rr + (c-4q)
  const float cq = (float)(c - 4*q);
  float p_m[12], sg_m[12], mn_m[12], one_m[12];
  #pragma unroll
  for (int d = 0; d < 3; ++d)
    #pragma unroll
    for (int rr = 0; rr < 4; ++rr) {
      int j = d*4 + rr;
      float p  = cq + (float)(16*d - 12 - rr);
      float ap = fabsf(p);
      bool  ok = ap <= 12.f;
      p_m[j]  = ok ? p : 0.f;
      sg_m[j] = ok ? fminf(fmaxf(p, -1.f), 1.f) : 0.f;
      mn_m[j] = ok ? (12.f - ap) : 0.f;    // mnj = 12-|dj-12|
      one_m[j]= ok ? 1.f : 0.f;
    }

  float gx[2][4], gy[2][4];
  #pragma unroll
  for (int t = 0; t < 2; ++t)
    #pragma unroll
    for (int rr = 0; rr < 4; ++rr) { gx[t][rr] = 0.f; gy[t][rr] = 0.f; }

  const _Float16* bBase = c16 + g0*2048 + (size_t)l*8;
  const int diLo = half ? 13 : 0;
  const int diHi = half ? 25 : 13;

  #pragma unroll 1
  for (int di = diLo; di < diHi; ++di) {
    const int r = h + di - PAD;          // 0..399
    const _Float16* rowB = bBase + (size_t)r*ROWE;

    f32x4 acc[2][3];
    #pragma unroll
    for (int t = 0; t < 2; ++t)
      #pragma unroll
      for (int d = 0; d < 3; ++d) acc[t][d] = (f32x4){0.f,0.f,0.f,0.f};

    #pragma unroll
    for (int ks = 0; ks < 4; ++ks) {
      half8 B0 = *(const half8*)(rowB + 0*2048 + ks*512);
      half8 B1 = *(const half8*)(rowB + 1*2048 + ks*512);
      half8 B2 = *(const half8*)(rowB + 2*2048 + ks*512);
      half8 B3 = *(const half8*)(rowB + 3*2048 + ks*512);
      acc[0][0] = __builtin_amdgcn_mfma_f32_16x16x32_f16(A[0][ks], B0, acc[0][0], 0,0,0);
      acc[0][1] = __builtin_amdgcn_mfma_f32_16x16x32_f16(A[0][ks], B1, acc[0][1], 0,0,0);
      acc[0][2] = __builtin_amdgcn_mfma_f32_16x16x32_f16(A[0][ks], B2, acc[0][2], 0,0,0);
      acc[1][0] = __builtin_amdgcn_mfma_f32_16x16x32_f16(A[1][ks], B1, acc[1][0], 0,0,0);
      acc[1][1] = __builtin_amdgcn_mfma_f32_16x16x32_f16(A[1][ks], B2, acc[1][1], 0,0,0);
      acc[1][2] = __builtin_amdgcn_mfma_f32_16x16x32_f16(A[1][ks], B3, acc[1][2], 0,0,0);
    }

    // per-di weights (ii/sdi/dif wave-uniform -> SALU): 3 VALU per slot-12
    const float ii  = (float)((di <= 12) ? di : 24 - di);
    const float sdi = (float)((di > 12) - (di < 12));
    const float dif = (float)(di - 12);
    float kx[12], ky[12];
    #pragma unroll
    for (int j = 0; j < 12; ++j) {
      kx[j] = fmaf(sg_m[j], ii, p_m[j]);
      ky[j] = fmaf(sdi, mn_m[j], dif*one_m[j]);
    }

    #pragma unroll
    for (int t = 0; t < 2; ++t)
      #pragma unroll
      for (int d = 0; d < 3; ++d)
        #pragma unroll
        for (int rr = 0; rr < 4; ++rr) {
          int   j   = d*4 + rr;
          float sad = acos_clip(acc[t][d][rr]);   // cos from unit vectors
          gx[t][rr] = fmaf(sad, kx[j], gx[t][rr]);
          gy[t][rr] = fmaf(sad, ky[j], gy[t][rr]);
        }
  }

  // reduce over c (lane bits 0..3); writer lanes c == rr store partials
  const int hoff = half*NP + h*HW;
  #pragma unroll
  for (int t = 0; t < 2; ++t)
    #pragma unroll
    for (int rr = 0; rr < 4; ++rr) {
      float sgx = gx[t][rr], sgy = gy[t][rr];
      #pragma unroll
      for (int m = 1; m < 16; m <<= 1) {
        sgx += __shfl_xor(sgx, m);
        sgy += __shfl_xor(sgy, m);
      }
      if (c == rr) {
        int w = w0 + 16*t + 4*q + rr;    // <= 395
        gxp[hoff + w] = sgx;
        gyp[hoff + w] = sgy;
      }
    }
}

// ---------------- Phase 3a: combine halves + global max ----------------
__global__ void combine_kernel(float* __restrict__ gxp,
                               const float* __restrict__ gyp,
                               unsigned* __restrict__ gmax) {
  __shared__ float wm[4];
  int idx = blockIdx.x*256 + threadIdx.x;      // 625*256 = NP exactly
  int hh = idx / HW;
  int ww = idx - hh*HW;
  float e = 0.f;
  if (hh >= PAD && hh < IEND && ww >= PAD && ww < IEND)
    e = fabsf(gxp[idx] + gxp[NP + idx]) + fabsf(gyp[idx] + gyp[NP + idx]);
  gxp[idx] = e;                                // edge buffer aliases gxp[0]
  float m = e;
  #pragma unroll
  for (int off = 1; off < 64; off <<= 1) m = fmaxf(m, __shfl_xor(m, off));
  if ((threadIdx.x & 63) == 0) wm[threadIdx.x >> 6] = m;
  __syncthreads();
  if (threadIdx.x == 0) {
    float mm = fmaxf(fmaxf(wm[0], wm[1]), fmaxf(wm[2], wm[3]));
    atomicMax(gmax, __float_as_uint(mm));      // e >= 0: uint order ok
  }
}

// ---------------- Phase 3b: normalize ----------------
__global__ void norm_kernel(const float* __restrict__ edge,
                            const unsigned* __restrict__ gmax,
                            float* __restrict__ out) {
  int idx = blockIdx.x*256 + threadIdx.x;
  float mv = __uint_as_float(*gmax);
  out[idx] = edge[idx] / mv;                   // border already 0
}

// ---------------- launch ----------------
extern "C" void kernel_launch(void* const* d_in, const int* in_sizes, int n_in,
                              void* d_out, int out_size, void* d_ws, size_t ws_size,
                              hipStream_t stream) {
  const float* cube = (const float*)d_in[0];   // (1,400,400,128) f32
  char* ws = (char*)d_ws;
  _Float16* c16  = (_Float16*)(ws);                     // 42,598,400 B
  float*    gxp  = (float*)(ws + 42598400);             // 2*NP floats
  float*    gyp  = (float*)(ws + 42598400 + 8*NP);      // 2*NP floats
  unsigned* gmax = (unsigned*)(ws + 42598400 + 16*NP);  // 4 B  (~45.2 MB total)

  cvt_kernel<<<dim3(26, 400), 256, 0, stream>>>(cube, c16, gmax);
  edge_kernel<<<2256, 256, 0, stream>>>(c16, gxp, gyp);
  combine_kernel<<<NP/256, 256, 0, stream>>>(gxp, gyp, gmax);
  norm_kernel<<<NP/256, 256, 0, stream>>>(gxp, gmax, (float*)d_out);
}